// Round 16
// baseline (1824.767 us; speedup 1.0000x reference)
//
#include <hip/hip_runtime.h>
#include <hip/hip_bf16.h>
#include <stdint.h>
#include <math.h>

// POD_GalerkinTransformer forward, MI355X (gfx950).
// fp16 MFMA pipeline (R7 numerics). R16 = R15 with ONE change: k_gemm family
// moves to BK=64 implemented as two proven BK=32 sub-tiles per buffer
// (half the barrier-pairs per K; 32 MFMAs between barriers). LDS 64KiB,
// still 2 blocks/CU. gemmG and all aux kernels unchanged (R15/R10-exact).

typedef _Float16 f16x8 __attribute__((ext_vector_type(8)));
typedef float f32x4 __attribute__((ext_vector_type(4)));
typedef unsigned short u16x8 __attribute__((ext_vector_type(8)));
typedef unsigned short u16;

#define SEQ 4096
#define NTOK 16384
#define HID 512
#define RSCL 256.0f
#define RSCLI (1.0f/256.0f)

__device__ __forceinline__ float wred(float x) {
#pragma unroll
  for (int off = 32; off; off >>= 1) x += __shfl_xor(x, off);
  return x;
}

__device__ __forceinline__ u16 f2h(float v) {
  _Float16 h = (_Float16)v;
  return __builtin_bit_cast(u16, h);
}
__device__ __forceinline__ float h2f(u16 u) {
  return (float)__builtin_bit_cast(_Float16, u);
}

__device__ __forceinline__ float fgelu(float a) {
  float t = 0.7978845608f * a * (1.0f + 0.044715f * a * a);
  float e = __expf(2.0f * t);
  float th = 1.0f - 2.0f / (e + 1.0f);
  return 0.5f * a * (1.0f + th);
}

__device__ __forceinline__ void gload16(const void* g, void* l) {
  __builtin_amdgcn_global_load_lds(
      reinterpret_cast<const __attribute__((address_space(1))) int*>(
          reinterpret_cast<uintptr_t>(g)),
      reinterpret_cast<__attribute__((address_space(3))) int*>(
          reinterpret_cast<uintptr_t>(l)),
      16, 0, 0);
}

// paired-row swizzle: 2 rows x 64B -> 8 x 16B slots, slot ^= (pair&7).
__device__ __forceinline__ void stS(const u16* g, int ldk, int rowBase, int k0,
                                    short* lds, int c) {
  int pr = c >> 3, s8 = (c & 7) ^ (pr & 7);
  int r = pr * 2 + (s8 >> 2);
  gload16(g + (size_t)(rowBase + r) * ldk + k0 + (s8 & 3) * 8, lds + c * 8);
}
__device__ __forceinline__ int idxg(int row, int grp) {
  int pr = row >> 1;
  int s8 = ((((row & 1) << 2) | grp) ^ (pr & 7));
  return pr * 64 + s8 * 8;
}

// ------- weight transpose+cast: [D][K][N] f32 -> [D][N][K] fp16 ------------
__global__ __launch_bounds__(256) void k_transpose(const float* __restrict__ src,
                                                   u16* __restrict__ dst,
                                                   int K, int N) {
  int d = blockIdx.z;
  const float* s = src + (size_t)d * K * N;
  u16* o = dst + (size_t)d * N * K;
  int k0 = blockIdx.x * 64, n0 = blockIdx.y * 64;
  __shared__ float tile[64][65];
  int t = threadIdx.x, c = t & 63, r4 = t >> 6;
#pragma unroll
  for (int i = 0; i < 16; ++i) {
    int r = i * 4 + r4;
    tile[r][c] = s[(size_t)(k0 + r) * N + n0 + c];
  }
  __syncthreads();
#pragma unroll
  for (int i = 0; i < 16; ++i) {
    int r = i * 4 + r4;
    o[(size_t)(n0 + r) * K + k0 + c] = f2h(tile[c][r]);
  }
}

// ------- pack x ------------------------------------------------------------
__global__ __launch_bounds__(256) void k_packx(const float* __restrict__ x,
                                               u16* __restrict__ XP) {
  int idx = blockIdx.x * 256 + threadIdx.x;
  int k = idx & 127, row = idx >> 7;
  int b = row >> 12, n = row & 4095;
  int tt = k >> 1, c = k & 1;
  XP[idx] = f2h(x[(((size_t)(b * 64 + tt)) * SEQ + n) * 2 + c]);
}

// ------- LayerNorm ---------------------------------------------------------
__global__ __launch_bounds__(256) void k_ln(const float* __restrict__ H,
                                            const float* __restrict__ G,
                                            const float* __restrict__ B,
                                            u16* __restrict__ Y) {
  int t = threadIdx.x, lane = t & 63;
  int row = blockIdx.x * 4 + (t >> 6);
  const float4* h4 = (const float4*)(H + (size_t)row * HID);
  float4 a = h4[lane * 2], b = h4[lane * 2 + 1];
  float v[8] = {a.x, a.y, a.z, a.w, b.x, b.y, b.z, b.w};
  float s = v[0] + v[1] + v[2] + v[3] + v[4] + v[5] + v[6] + v[7];
  s = wred(s);
  float m = s * (1.0f / 512.0f);
  float q = 0.f;
#pragma unroll
  for (int i = 0; i < 8; ++i) {
    v[i] -= m;
    q += v[i] * v[i];
  }
  q = wred(q);
  float rs = rsqrtf(q * (1.0f / 512.0f) + 1e-5f);
  const float4* g4 = (const float4*)G;
  const float4* b4 = (const float4*)B;
  float4 g1 = g4[lane * 2], g2 = g4[lane * 2 + 1];
  float4 e1 = b4[lane * 2], e2 = b4[lane * 2 + 1];
  float gg[8] = {g1.x, g1.y, g1.z, g1.w, g2.x, g2.y, g2.z, g2.w};
  float ee[8] = {e1.x, e1.y, e1.z, e1.w, e2.x, e2.y, e2.z, e2.w};
  union { u16x8 v; u16 s_[8]; } uh;
#pragma unroll
  for (int i = 0; i < 8; ++i) uh.s_[i] = f2h(v[i] * rs * gg[i] + ee[i]);
  *reinterpret_cast<u16x8*>((u16*)Y + (size_t)row * HID + lane * 8) = uh.v;
}

// ------- dots partials: 16 chunks x 256 rows (R15-exact) -------------------
__global__ __launch_bounds__(256) void k_dots(const u16* __restrict__ QKV,
                                              float* __restrict__ DOTSP) {
  int bh = blockIdx.y, b = bh >> 3, h = bh & 7;
  int n0 = blockIdx.x * 256;
  __shared__ alignas(16) short ks[64 * 64];
  __shared__ alignas(16) short vs[64 * 64];
  int t = threadIdx.x;
  int d0 = (t & 15) * 4, e0 = (t >> 4) * 4;
  float acc[4][4] = {};
  for (int sub = 0; sub < 4; ++sub) {
    int nb = n0 + sub * 64;
#pragma unroll
    for (int i = 0; i < 2; ++i) {
      int c = t + i * 256;
      int r = c >> 3, off = (c & 7) << 3;
      const u16* base = QKV + (size_t)(b * SEQ + nb + r) * 1536;
      gload16(base + 512 + h * 64 + off, ks + c * 8);
      gload16(base + 1024 + h * 64 + off, vs + c * 8);
    }
    asm volatile("s_waitcnt vmcnt(0)" ::: "memory");
    __syncthreads();
    for (int r = 0; r < 64; ++r) {
      short4 kk = *(const short4*)&ks[r * 64 + d0];
      short4 vv = *(const short4*)&vs[r * 64 + e0];
      float kf[4] = {h2f((u16)kk.x), h2f((u16)kk.y), h2f((u16)kk.z), h2f((u16)kk.w)};
      float vf[4] = {h2f((u16)vv.x), h2f((u16)vv.y), h2f((u16)vv.z), h2f((u16)vv.w)};
#pragma unroll
      for (int i = 0; i < 4; ++i)
#pragma unroll
        for (int j = 0; j < 4; ++j) acc[i][j] += kf[i] * vf[j];
    }
    __syncthreads();
  }
  float* dst = DOTSP + ((size_t)blockIdx.x * 32 + bh) * 4096;
#pragma unroll
  for (int i = 0; i < 4; ++i)
#pragma unroll
    for (int j = 0; j < 4; ++j) dst[(d0 + i) * 64 + e0 + j] = acc[i][j];
}

__global__ __launch_bounds__(256) void k_reddots(const float* __restrict__ P,
                                                 float* __restrict__ D) {
  int i = blockIdx.x * 256 + threadIdx.x;
  float s = 0.f;
#pragma unroll
  for (int c = 0; c < 16; ++c) s += P[(size_t)c * 131072 + i];
  D[i] = s;
}

// ------- o = q @ dots * (1/n) (R10-exact) ----------------------------------
__global__ __launch_bounds__(256) void k_ov(const u16* __restrict__ QKV,
                                            const float* __restrict__ DOTS,
                                            u16* __restrict__ O) {
  int bh = blockIdx.y, b = bh >> 3, h = bh & 7;
  int n0 = blockIdx.x * 64;
  __shared__ alignas(16) float ds[64 * 64];
  __shared__ alignas(16) short qs[64 * 64];
  int t = threadIdx.x;
  const float* dsrc = DOTS + (size_t)bh * 4096;
#pragma unroll
  for (int i = 0; i < 16; ++i) ds[t + i * 256] = dsrc[t + i * 256];
#pragma unroll
  for (int i = 0; i < 2; ++i) {
    int c = t + i * 256, r = c >> 3, off = (c & 7) << 3;
    gload16(QKV + (size_t)(b * SEQ + n0 + r) * 1536 + h * 64 + off, qs + c * 8);
  }
  asm volatile("s_waitcnt vmcnt(0)" ::: "memory");
  __syncthreads();
  int wv = t >> 6, lane = t & 63;
  for (int tok = wv; tok < 64; tok += 4) {
    float acc = 0.f;
#pragma unroll
    for (int d = 0; d < 64; d += 4) {
      short4 q4 = *(const short4*)&qs[tok * 64 + d];
      acc += h2f((u16)q4.x) * ds[(d + 0) * 64 + lane];
      acc += h2f((u16)q4.y) * ds[(d + 1) * 64 + lane];
      acc += h2f((u16)q4.z) * ds[(d + 2) * 64 + lane];
      acc += h2f((u16)q4.w) * ds[(d + 3) * 64 + lane];
    }
    O[(size_t)(b * SEQ + n0 + tok) * 512 + h * 64 + lane] = f2h(acc * (1.0f / SEQ));
  }
}

// ======== 128x128 GEMM, BK=64 (two proven BK=32 sub-tiles per buffer) ======
// MODE 0: H = (acc + bias)*sqrt(512) + posenc   (K=128 -> NT=2)
// MODE 1: fused inorm on k/v head groups -> QKV fp16
// MODE 2: H = acc*ascale + bias + Hin; o16 = fp16(H/256)
// MODE 7: out32[b, col*4096+n] = 256*acc + bias
template <int MODE>
__global__ __launch_bounds__(256, 2) void k_gemm(
    const u16* __restrict__ A, const u16* __restrict__ B1, int K,
    const float* __restrict__ bias, const float* __restrict__ Hin,
    float ascale, float* __restrict__ out32, u16* __restrict__ o16, int ldo) {
  // sm[buf][tile][seg*4096 + ...]: tile 0=A, 1=B; seg 0=k-lo, 1=k-hi. 64 KiB.
  __shared__ alignas(16) short sm[2][2][8192];
  const int t = threadIdx.x, lane = t & 63;
  const int wv = t >> 6, wr = wv >> 1, wc = wv & 1;
  const int r16 = lane & 15, grp = lane >> 4;
  const int mBase = blockIdx.y * 128, nBase = blockIdx.x * 128;
  const int NT = K >> 6;

  f32x4 acc[4][4] = {};

  auto stage_all = [&](int sb, int k0) {          // 8 loads/thread
    stS(A, K, mBase, k0, &sm[sb][0][0], t);
    stS(A, K, mBase, k0, &sm[sb][0][0], t + 256);
    stS(A, K, mBase, k0 + 32, &sm[sb][0][4096], t);
    stS(A, K, mBase, k0 + 32, &sm[sb][0][4096], t + 256);
    stS(B1, K, nBase, k0, &sm[sb][1][0], t);
    stS(B1, K, nBase, k0, &sm[sb][1][0], t + 256);
    stS(B1, K, nBase, k0 + 32, &sm[sb][1][4096], t);
    stS(B1, K, nBase, k0 + 32, &sm[sb][1][4096], t + 256);
  };

  stage_all(0, 0);
  stage_all(1, 64);

  for (int kt = 0; kt < NT; ++kt) {
    const int cur = kt & 1;
    if (kt + 1 < NT) asm volatile("s_waitcnt vmcnt(8)" ::: "memory");
    else             asm volatile("s_waitcnt vmcnt(0)" ::: "memory");
    __builtin_amdgcn_s_barrier();
    // ---- k-lo sub-tile
    {
      f16x8 af[4], bv[4];
#pragma unroll
      for (int f = 0; f < 4; ++f)
        af[f] = *(const f16x8*)&sm[cur][0][idxg(wr * 64 + f * 16 + r16, grp)];
#pragma unroll
      for (int f = 0; f < 4; ++f)
        bv[f] = *(const f16x8*)&sm[cur][1][idxg(wc * 64 + f * 16 + r16, grp)];
      __builtin_amdgcn_s_setprio(1);
#pragma unroll
      for (int i = 0; i < 4; ++i)
#pragma unroll
        for (int j = 0; j < 4; ++j)
          acc[i][j] = __builtin_amdgcn_mfma_f32_16x16x32_f16(af[i], bv[j], acc[i][j], 0, 0, 0);
      __builtin_amdgcn_s_setprio(0);
    }
    // ---- k-hi sub-tile
    {
      f16x8 af[4], bv[4];
#pragma unroll
      for (int f = 0; f < 4; ++f)
        af[f] = *(const f16x8*)&sm[cur][0][4096 + idxg(wr * 64 + f * 16 + r16, grp)];
#pragma unroll
      for (int f = 0; f < 4; ++f)
        bv[f] = *(const f16x8*)&sm[cur][1][4096 + idxg(wc * 64 + f * 16 + r16, grp)];
      __builtin_amdgcn_s_setprio(1);
#pragma unroll
      for (int i = 0; i < 4; ++i)
#pragma unroll
        for (int j = 0; j < 4; ++j)
          acc[i][j] = __builtin_amdgcn_mfma_f32_16x16x32_f16(af[i], bv[j], acc[i][j], 0, 0, 0);
      __builtin_amdgcn_s_setprio(0);
    }
    asm volatile("s_waitcnt lgkmcnt(0)" ::: "memory");
    __builtin_amdgcn_s_barrier();
    if (kt + 2 < NT) stage_all(cur, (kt + 2) << 6);
  }

  if constexpr (MODE == 1) {
    const bool doNorm = (nBase >= 512);
#pragma unroll
    for (int i = 0; i < 4; ++i) {
#pragma unroll
      for (int r = 0; r < 4; ++r) {
        float s = 0.f, s2 = 0.f;
#pragma unroll
        for (int j = 0; j < 4; ++j) {
          float v = acc[i][j][r];
          s += v;
          s2 += v * v;
        }
#pragma unroll
        for (int off = 8; off; off >>= 1) {
          s += __shfl_xor(s, off);
          s2 += __shfl_xor(s2, off);
        }
        float m = s * (1.0f / 64.0f);
        float var = fmaxf(s2 * (1.0f / 64.0f) - m * m, 0.f);
        float rs = rsqrtf(var + 1e-5f);
        int row = mBase + wr * 64 + i * 16 + grp * 4 + r;
#pragma unroll
        for (int j = 0; j < 4; ++j) {
          int col = nBase + wc * 64 + j * 16 + r16;
          float v = acc[i][j][r];
          if (doNorm) v = (v - m) * rs;
          o16[(size_t)row * ldo + col] = f2h(v);
        }
      }
    }
    return;
  }

#pragma unroll
  for (int i = 0; i < 4; ++i) {
#pragma unroll
    for (int j = 0; j < 4; ++j) {
#pragma unroll
      for (int r = 0; r < 4; ++r) {
        int row = mBase + wr * 64 + i * 16 + grp * 4 + r;
        int col = nBase + wc * 64 + j * 16 + r16;
        float v = acc[i][j][r];
        if constexpr (MODE == 0) {
          v = (v + bias[col]) * 22.627416997969522f;
          int n = row & (SEQ - 1);
          int k2 = col >> 1;
          float ang = (float)n * expf((float)k2 * -0.03597789207803197f);
          v += (col & 1) ? cosf(ang) : sinf(ang);
          out32[(size_t)row * HID + col] = v;
        } else if constexpr (MODE == 2) {
          v = v * ascale + bias[col] + Hin[(size_t)row * HID + col];
          out32[(size_t)row * HID + col] = v;
          o16[(size_t)row * HID + col] = f2h(v * RSCLI);
        } else {  // MODE 7
          v = v * RSCL + bias[col];
          out32[(size_t)(row >> 12) * (128 * 4096) + (size_t)col * SEQ + (row & 4095)] = v;
        }
      }
    }
  }
}

// ======== gated 128x256 counted-pipeline kernel (R10-exact) ================
__global__ __launch_bounds__(512, 2) void k_gemmG(
    const u16* __restrict__ A, int lda,
    const u16* __restrict__ B1, const u16* __restrict__ B2, int K,
    const float* __restrict__ bias, u16* __restrict__ o16, int ldo) {
  __shared__ alignas(16) short sm[2][20480];  // A 8KB | B1 16KB | B2 16KB per buf
  const int t = threadIdx.x, lane = t & 63;
  const int w = t >> 6, wr = w >> 2, wcn = w & 3;
  const int r16 = lane & 15, grp = lane >> 4;
  const int mBase = blockIdx.y * 128, nBase = blockIdx.x * 256;
  const int NT = K >> 5;

  f32x4 acc[4][4] = {};
  f32x4 acc2[4][4] = {};

  auto stage_all = [&](int sb, int k0) {          // G = 5 loads/thread
    stS(A, lda, mBase, k0, &sm[sb][0], t);
    stS(B1, K, nBase, k0, &sm[sb][4096], t);
    stS(B1, K, nBase, k0, &sm[sb][4096], t + 512);
    stS(B2, K, nBase, k0, &sm[sb][12288], t);
    stS(B2, K, nBase, k0, &sm[sb][12288], t + 512);
  };

  stage_all(0, 0);
  stage_all(1, 32);

  for (int kt = 0; kt < NT; ++kt) {
    const int cur = kt & 1;
    if (kt + 1 < NT) asm volatile("s_waitcnt vmcnt(5)" ::: "memory");
    else             asm volatile("s_waitcnt vmcnt(0)" ::: "memory");
    __builtin_amdgcn_s_barrier();
    f16x8 af[4], b1v[4], b2v[4];
#pragma unroll
    for (int i = 0; i < 4; ++i)
      af[i] = *(const f16x8*)&sm[cur][idxg(wr * 64 + i * 16 + r16, grp)];
#pragma unroll
    for (int j = 0; j < 4; ++j) {
      int ro = idxg(wcn * 64 + j * 16 + r16, grp);
      b1v[j] = *(const f16x8*)&sm[cur][4096 + ro];
      b2v[j] = *(const f16x8*)&sm[cur][12288 + ro];
    }
    __builtin_amdgcn_s_setprio(1);
#pragma unroll
    for (int i = 0; i < 4; ++i)
#pragma unroll
      for (int j = 0; j < 4; ++j) {
        acc[i][j] = __builtin_amdgcn_mfma_f32_16x16x32_f16(af[i], b1v[j], acc[i][j], 0, 0, 0);
        acc2[i][j] = __builtin_amdgcn_mfma_f32_16x16x32_f16(af[i], b2v[j], acc2[i][j], 0, 0, 0);
      }
    __builtin_amdgcn_s_setprio(0);
    asm volatile("s_waitcnt lgkmcnt(0)" ::: "memory");
    __builtin_amdgcn_s_barrier();
    if (kt + 2 < NT) stage_all(cur, (kt + 2) << 5);
  }

#pragma unroll
  for (int i = 0; i < 4; ++i) {
#pragma unroll
    for (int j = 0; j < 4; ++j) {
#pragma unroll
      for (int r = 0; r < 4; ++r) {
        int row = mBase + wr * 64 + i * 16 + grp * 4 + r;
        int col = nBase + wcn * 64 + j * 16 + r16;
        float a = acc[i][j][r] * RSCL + bias[col];
        float c2 = acc2[i][j][r] * RSCL + bias[2048 + col];
        o16[(size_t)row * ldo + col] = f2h(fgelu(a) * c2 * RSCLI);
      }
    }
  }
}

// ---------------------------------------------------------------------------
extern "C" void kernel_launch(void* const* d_in, const int* in_sizes, int n_in,
                              void* d_out, int out_size, void* d_ws, size_t ws_size,
                              hipStream_t stream) {
  const float* x    = (const float*)d_in[0];
  const float* Wemb = (const float*)d_in[1];
  const float* bemb = (const float*)d_in[2];
  const float* lng  = (const float*)d_in[3];
  const float* lnb  = (const float*)d_in[4];
  const float* Wqkv = (const float*)d_in[5];
  const float* Wout = (const float*)d_in[6];
  const float* bout = (const float*)d_in[7];
  const float* W1   = (const float*)d_in[8];
  const float* b1   = (const float*)d_in[9];
  const float* W2   = (const float*)d_in[10];
  const float* b2   = (const float*)d_in[11];
  const float* Wd   = (const float*)d_in[12];
  const float* bd   = (const float*)d_in[13];

  char* p = (char*)d_ws;
  auto alloc = [&](size_t bytes) {
    char* r = p;
    p += (bytes + 255) & ~(size_t)255;
    return r;
  };
  u16* WembT = (u16*)alloc((size_t)512 * 128 * 2);
  u16* WqkvT = (u16*)alloc((size_t)6 * 1536 * 512 * 2);
  u16* WoutT = (u16*)alloc((size_t)6 * 512 * 512 * 2);
  u16* W1T   = (u16*)alloc((size_t)6 * 4096 * 512 * 2);
  u16* W2T   = (u16*)alloc((size_t)6 * 512 * 2048 * 2);
  u16* WdT   = (u16*)alloc((size_t)128 * 512 * 2);
  float* H   = (float*)alloc((size_t)NTOK * 512 * 4);
  u16* HB    = (u16*)alloc((size_t)NTOK * 512 * 2);
  float* DOTSP = (float*)alloc((size_t)16 * 32 * 4096 * 4);
  float* DOTS  = (float*)alloc((size_t)32 * 4096 * 4);
  char* U = alloc((size_t)64 * 1024 * 1024);
  const size_t MI = 1024 * 1024;
  u16* XP  = (u16*)U;
  u16* Y   = (u16*)U;
  u16* QKV = (u16*)(U + 16 * MI);
  u16* O   = (u16*)U;
  u16* F   = (u16*)U;

  k_transpose<<<dim3(2, 8, 1),  256, 0, stream>>>(Wemb, WembT, 128, 512);
  k_transpose<<<dim3(8, 24, 6), 256, 0, stream>>>(Wqkv, WqkvT, 512, 1536);
  k_transpose<<<dim3(8, 8, 6),  256, 0, stream>>>(Wout, WoutT, 512, 512);
  k_transpose<<<dim3(8, 64, 6), 256, 0, stream>>>(W1, W1T, 512, 4096);
  k_transpose<<<dim3(32, 8, 6), 256, 0, stream>>>(W2, W2T, 2048, 512);
  k_transpose<<<dim3(8, 2, 1),  256, 0, stream>>>(Wd, WdT, 512, 128);

  k_packx<<<8192, 256, 0, stream>>>(x, XP);
  k_gemm<0><<<dim3(4, 128), 256, 0, stream>>>(XP, WembT, 128, bemb,
      nullptr, 1.f, H, nullptr, 0);

  for (int i = 0; i < 6; ++i) {
    k_ln<<<4096, 256, 0, stream>>>(H, lng + i * 512, lnb + i * 512, Y);
    k_gemm<1><<<dim3(12, 128), 256, 0, stream>>>(Y,
        WqkvT + (size_t)i * 1536 * 512, 512, nullptr, nullptr, 1.f,
        nullptr, QKV, 1536);
    k_dots<<<dim3(16, 32), 256, 0, stream>>>(QKV, DOTSP);
    k_reddots<<<512, 256, 0, stream>>>(DOTSP, DOTS);
    k_ov<<<dim3(64, 32), 256, 0, stream>>>(QKV, DOTS, O);
    k_gemm<2><<<dim3(4, 128), 256, 0, stream>>>(O,
        WoutT + (size_t)i * 512 * 512, 512, bout + i * 512, H, 1.f, H, HB, 512);
    k_gemmG<<<dim3(8, 128), 512, 0, stream>>>(HB, 512,
        W1T + (size_t)i * 4096 * 512,
        W1T + (size_t)i * 4096 * 512 + (size_t)2048 * 512, 512,
        b1 + i * 4096, F, 2048);
    k_gemm<2><<<dim3(4, 128), 256, 0, stream>>>(F,
        W2T + (size_t)i * 512 * 2048, 2048, b2 + i * 512, H, RSCL, H, HB, 512);
  }
  k_gemm<7><<<dim3(1, 128), 256, 0, stream>>>(HB, WdT, 512, bd,
      nullptr, 1.f, (float*)d_out, nullptr, 0);
}

// Round 17
// 1809.026 us; speedup vs baseline: 1.0087x; 1.0087x over previous
//
#include <hip/hip_runtime.h>
#include <hip/hip_bf16.h>
#include <stdint.h>
#include <math.h>

// POD_GalerkinTransformer forward, MI355X (gfx950).
// fp16 MFMA pipeline (R7 numerics). R17 = R15-exact (best measured: 1810us).
// GEMMs: 128-tile BK=32 counted-vmcnt double-buffer (m233-ceiling ~600TF —
// all 7 structure grafts nulled; escape requires the m201 8-phase template
// which twice failed safe porting). Aux: R10 structure + 16-chunk k_dots.

typedef _Float16 f16x8 __attribute__((ext_vector_type(8)));
typedef float f32x4 __attribute__((ext_vector_type(4)));
typedef unsigned short u16x8 __attribute__((ext_vector_type(8)));
typedef unsigned short u16;

#define SEQ 4096
#define NTOK 16384
#define HID 512
#define RSCL 256.0f
#define RSCLI (1.0f/256.0f)

__device__ __forceinline__ float wred(float x) {
#pragma unroll
  for (int off = 32; off; off >>= 1) x += __shfl_xor(x, off);
  return x;
}

__device__ __forceinline__ u16 f2h(float v) {
  _Float16 h = (_Float16)v;
  return __builtin_bit_cast(u16, h);
}
__device__ __forceinline__ float h2f(u16 u) {
  return (float)__builtin_bit_cast(_Float16, u);
}

__device__ __forceinline__ float fgelu(float a) {
  float t = 0.7978845608f * a * (1.0f + 0.044715f * a * a);
  float e = __expf(2.0f * t);
  float th = 1.0f - 2.0f / (e + 1.0f);
  return 0.5f * a * (1.0f + th);
}

__device__ __forceinline__ void gload16(const void* g, void* l) {
  __builtin_amdgcn_global_load_lds(
      reinterpret_cast<const __attribute__((address_space(1))) int*>(
          reinterpret_cast<uintptr_t>(g)),
      reinterpret_cast<__attribute__((address_space(3))) int*>(
          reinterpret_cast<uintptr_t>(l)),
      16, 0, 0);
}

// paired-row swizzle: 2 rows x 64B -> 8 x 16B slots, slot ^= (pair&7).
__device__ __forceinline__ void stS(const u16* g, int ldk, int rowBase, int k0,
                                    short* lds, int c) {
  int pr = c >> 3, s8 = (c & 7) ^ (pr & 7);
  int r = pr * 2 + (s8 >> 2);
  gload16(g + (size_t)(rowBase + r) * ldk + k0 + (s8 & 3) * 8, lds + c * 8);
}
__device__ __forceinline__ int idxg(int row, int grp) {
  int pr = row >> 1;
  int s8 = ((((row & 1) << 2) | grp) ^ (pr & 7));
  return pr * 64 + s8 * 8;
}

// ------- weight transpose+cast: [D][K][N] f32 -> [D][N][K] fp16 ------------
__global__ __launch_bounds__(256) void k_transpose(const float* __restrict__ src,
                                                   u16* __restrict__ dst,
                                                   int K, int N) {
  int d = blockIdx.z;
  const float* s = src + (size_t)d * K * N;
  u16* o = dst + (size_t)d * N * K;
  int k0 = blockIdx.x * 64, n0 = blockIdx.y * 64;
  __shared__ float tile[64][65];
  int t = threadIdx.x, c = t & 63, r4 = t >> 6;
#pragma unroll
  for (int i = 0; i < 16; ++i) {
    int r = i * 4 + r4;
    tile[r][c] = s[(size_t)(k0 + r) * N + n0 + c];
  }
  __syncthreads();
#pragma unroll
  for (int i = 0; i < 16; ++i) {
    int r = i * 4 + r4;
    o[(size_t)(n0 + r) * K + k0 + c] = f2h(tile[c][r]);
  }
}

// ------- pack x ------------------------------------------------------------
__global__ __launch_bounds__(256) void k_packx(const float* __restrict__ x,
                                               u16* __restrict__ XP) {
  int idx = blockIdx.x * 256 + threadIdx.x;
  int k = idx & 127, row = idx >> 7;
  int b = row >> 12, n = row & 4095;
  int tt = k >> 1, c = k & 1;
  XP[idx] = f2h(x[(((size_t)(b * 64 + tt)) * SEQ + n) * 2 + c]);
}

// ------- LayerNorm ---------------------------------------------------------
__global__ __launch_bounds__(256) void k_ln(const float* __restrict__ H,
                                            const float* __restrict__ G,
                                            const float* __restrict__ B,
                                            u16* __restrict__ Y) {
  int t = threadIdx.x, lane = t & 63;
  int row = blockIdx.x * 4 + (t >> 6);
  const float4* h4 = (const float4*)(H + (size_t)row * HID);
  float4 a = h4[lane * 2], b = h4[lane * 2 + 1];
  float v[8] = {a.x, a.y, a.z, a.w, b.x, b.y, b.z, b.w};
  float s = v[0] + v[1] + v[2] + v[3] + v[4] + v[5] + v[6] + v[7];
  s = wred(s);
  float m = s * (1.0f / 512.0f);
  float q = 0.f;
#pragma unroll
  for (int i = 0; i < 8; ++i) {
    v[i] -= m;
    q += v[i] * v[i];
  }
  q = wred(q);
  float rs = rsqrtf(q * (1.0f / 512.0f) + 1e-5f);
  const float4* g4 = (const float4*)G;
  const float4* b4 = (const float4*)B;
  float4 g1 = g4[lane * 2], g2 = g4[lane * 2 + 1];
  float4 e1 = b4[lane * 2], e2 = b4[lane * 2 + 1];
  float gg[8] = {g1.x, g1.y, g1.z, g1.w, g2.x, g2.y, g2.z, g2.w};
  float ee[8] = {e1.x, e1.y, e1.z, e1.w, e2.x, e2.y, e2.z, e2.w};
  union { u16x8 v; u16 s_[8]; } uh;
#pragma unroll
  for (int i = 0; i < 8; ++i) uh.s_[i] = f2h(v[i] * rs * gg[i] + ee[i]);
  *reinterpret_cast<u16x8*>((u16*)Y + (size_t)row * HID + lane * 8) = uh.v;
}

// ------- dots partials: 16 chunks x 256 rows -------------------------------
__global__ __launch_bounds__(256) void k_dots(const u16* __restrict__ QKV,
                                              float* __restrict__ DOTSP) {
  int bh = blockIdx.y, b = bh >> 3, h = bh & 7;
  int n0 = blockIdx.x * 256;
  __shared__ alignas(16) short ks[64 * 64];
  __shared__ alignas(16) short vs[64 * 64];
  int t = threadIdx.x;
  int d0 = (t & 15) * 4, e0 = (t >> 4) * 4;
  float acc[4][4] = {};
  for (int sub = 0; sub < 4; ++sub) {
    int nb = n0 + sub * 64;
#pragma unroll
    for (int i = 0; i < 2; ++i) {
      int c = t + i * 256;
      int r = c >> 3, off = (c & 7) << 3;
      const u16* base = QKV + (size_t)(b * SEQ + nb + r) * 1536;
      gload16(base + 512 + h * 64 + off, ks + c * 8);
      gload16(base + 1024 + h * 64 + off, vs + c * 8);
    }
    asm volatile("s_waitcnt vmcnt(0)" ::: "memory");
    __syncthreads();
    for (int r = 0; r < 64; ++r) {
      short4 kk = *(const short4*)&ks[r * 64 + d0];
      short4 vv = *(const short4*)&vs[r * 64 + e0];
      float kf[4] = {h2f((u16)kk.x), h2f((u16)kk.y), h2f((u16)kk.z), h2f((u16)kk.w)};
      float vf[4] = {h2f((u16)vv.x), h2f((u16)vv.y), h2f((u16)vv.z), h2f((u16)vv.w)};
#pragma unroll
      for (int i = 0; i < 4; ++i)
#pragma unroll
        for (int j = 0; j < 4; ++j) acc[i][j] += kf[i] * vf[j];
    }
    __syncthreads();
  }
  float* dst = DOTSP + ((size_t)blockIdx.x * 32 + bh) * 4096;
#pragma unroll
  for (int i = 0; i < 4; ++i)
#pragma unroll
    for (int j = 0; j < 4; ++j) dst[(d0 + i) * 64 + e0 + j] = acc[i][j];
}

__global__ __launch_bounds__(256) void k_reddots(const float* __restrict__ P,
                                                 float* __restrict__ D) {
  int i = blockIdx.x * 256 + threadIdx.x;
  float s = 0.f;
#pragma unroll
  for (int c = 0; c < 16; ++c) s += P[(size_t)c * 131072 + i];
  D[i] = s;
}

// ------- o = q @ dots * (1/n) ----------------------------------------------
__global__ __launch_bounds__(256) void k_ov(const u16* __restrict__ QKV,
                                            const float* __restrict__ DOTS,
                                            u16* __restrict__ O) {
  int bh = blockIdx.y, b = bh >> 3, h = bh & 7;
  int n0 = blockIdx.x * 64;
  __shared__ alignas(16) float ds[64 * 64];
  __shared__ alignas(16) short qs[64 * 64];
  int t = threadIdx.x;
  const float* dsrc = DOTS + (size_t)bh * 4096;
#pragma unroll
  for (int i = 0; i < 16; ++i) ds[t + i * 256] = dsrc[t + i * 256];
#pragma unroll
  for (int i = 0; i < 2; ++i) {
    int c = t + i * 256, r = c >> 3, off = (c & 7) << 3;
    gload16(QKV + (size_t)(b * SEQ + n0 + r) * 1536 + h * 64 + off, qs + c * 8);
  }
  asm volatile("s_waitcnt vmcnt(0)" ::: "memory");
  __syncthreads();
  int wv = t >> 6, lane = t & 63;
  for (int tok = wv; tok < 64; tok += 4) {
    float acc = 0.f;
#pragma unroll
    for (int d = 0; d < 64; d += 4) {
      short4 q4 = *(const short4*)&qs[tok * 64 + d];
      acc += h2f((u16)q4.x) * ds[(d + 0) * 64 + lane];
      acc += h2f((u16)q4.y) * ds[(d + 1) * 64 + lane];
      acc += h2f((u16)q4.z) * ds[(d + 2) * 64 + lane];
      acc += h2f((u16)q4.w) * ds[(d + 3) * 64 + lane];
    }
    O[(size_t)(b * SEQ + n0 + tok) * 512 + h * 64 + lane] = f2h(acc * (1.0f / SEQ));
  }
}

// ======== 128x128 counted-pipeline GEMM (BK=32, R10-exact) =================
template <int MODE>
__global__ __launch_bounds__(256, 2) void k_gemm(
    const u16* __restrict__ A, const u16* __restrict__ B1, int K,
    const float* __restrict__ bias, const float* __restrict__ Hin,
    float ascale, float* __restrict__ out32, u16* __restrict__ o16, int ldo) {
  __shared__ alignas(16) short sm[2][2][4096];   // 32 KiB
  const int t = threadIdx.x, lane = t & 63;
  const int wv = t >> 6, wr = wv >> 1, wc = wv & 1;
  const int r16 = lane & 15, grp = lane >> 4;
  const int mBase = blockIdx.y * 128, nBase = blockIdx.x * 128;
  const int NT = K >> 5;

  f32x4 acc[4][4] = {};

  auto stage_all = [&](int sb, int k0) {          // G = 4 loads/thread
    stS(A, K, mBase, k0, &sm[sb][0][0], t);
    stS(A, K, mBase, k0, &sm[sb][0][0], t + 256);
    stS(B1, K, nBase, k0, &sm[sb][1][0], t);
    stS(B1, K, nBase, k0, &sm[sb][1][0], t + 256);
  };

  stage_all(0, 0);
  stage_all(1, 32);

  for (int kt = 0; kt < NT; ++kt) {
    const int cur = kt & 1;
    if (kt + 1 < NT) asm volatile("s_waitcnt vmcnt(4)" ::: "memory");
    else             asm volatile("s_waitcnt vmcnt(0)" ::: "memory");
    __builtin_amdgcn_s_barrier();
    f16x8 af[4], bv[4];
#pragma unroll
    for (int f = 0; f < 4; ++f)
      af[f] = *(const f16x8*)&sm[cur][0][idxg(wr * 64 + f * 16 + r16, grp)];
#pragma unroll
    for (int f = 0; f < 4; ++f)
      bv[f] = *(const f16x8*)&sm[cur][1][idxg(wc * 64 + f * 16 + r16, grp)];
    __builtin_amdgcn_s_setprio(1);
#pragma unroll
    for (int i = 0; i < 4; ++i)
#pragma unroll
      for (int j = 0; j < 4; ++j)
        acc[i][j] = __builtin_amdgcn_mfma_f32_16x16x32_f16(af[i], bv[j], acc[i][j], 0, 0, 0);
    __builtin_amdgcn_s_setprio(0);
    asm volatile("s_waitcnt lgkmcnt(0)" ::: "memory");
    __builtin_amdgcn_s_barrier();
    if (kt + 2 < NT) stage_all(cur, (kt + 2) << 5);
  }

  if constexpr (MODE == 1) {
    const bool doNorm = (nBase >= 512);
#pragma unroll
    for (int i = 0; i < 4; ++i) {
#pragma unroll
      for (int r = 0; r < 4; ++r) {
        float s = 0.f, s2 = 0.f;
#pragma unroll
        for (int j = 0; j < 4; ++j) {
          float v = acc[i][j][r];
          s += v;
          s2 += v * v;
        }
#pragma unroll
        for (int off = 8; off; off >>= 1) {
          s += __shfl_xor(s, off);
          s2 += __shfl_xor(s2, off);
        }
        float m = s * (1.0f / 64.0f);
        float var = fmaxf(s2 * (1.0f / 64.0f) - m * m, 0.f);
        float rs = rsqrtf(var + 1e-5f);
        int row = mBase + wr * 64 + i * 16 + grp * 4 + r;
#pragma unroll
        for (int j = 0; j < 4; ++j) {
          int col = nBase + wc * 64 + j * 16 + r16;
          float v = acc[i][j][r];
          if (doNorm) v = (v - m) * rs;
          o16[(size_t)row * ldo + col] = f2h(v);
        }
      }
    }
    return;
  }

#pragma unroll
  for (int i = 0; i < 4; ++i) {
#pragma unroll
    for (int j = 0; j < 4; ++j) {
#pragma unroll
      for (int r = 0; r < 4; ++r) {
        int row = mBase + wr * 64 + i * 16 + grp * 4 + r;
        int col = nBase + wc * 64 + j * 16 + r16;
        float v = acc[i][j][r];
        if constexpr (MODE == 0) {
          v = (v + bias[col]) * 22.627416997969522f;
          int n = row & (SEQ - 1);
          int k2 = col >> 1;
          float ang = (float)n * expf((float)k2 * -0.03597789207803197f);
          v += (col & 1) ? cosf(ang) : sinf(ang);
          out32[(size_t)row * HID + col] = v;
        } else if constexpr (MODE == 2) {
          v = v * ascale + bias[col] + Hin[(size_t)row * HID + col];
          out32[(size_t)row * HID + col] = v;
          o16[(size_t)row * HID + col] = f2h(v * RSCLI);
        } else {  // MODE 7
          v = v * RSCL + bias[col];
          out32[(size_t)(row >> 12) * (128 * 4096) + (size_t)col * SEQ + (row & 4095)] = v;
        }
      }
    }
  }
}

// ======== gated 128x256 counted-pipeline kernel (R10-exact) ================
__global__ __launch_bounds__(512, 2) void k_gemmG(
    const u16* __restrict__ A, int lda,
    const u16* __restrict__ B1, const u16* __restrict__ B2, int K,
    const float* __restrict__ bias, u16* __restrict__ o16, int ldo) {
  __shared__ alignas(16) short sm[2][20480];  // A 8KB | B1 16KB | B2 16KB per buf
  const int t = threadIdx.x, lane = t & 63;
  const int w = t >> 6, wr = w >> 2, wcn = w & 3;
  const int r16 = lane & 15, grp = lane >> 4;
  const int mBase = blockIdx.y * 128, nBase = blockIdx.x * 256;
  const int NT = K >> 5;

  f32x4 acc[4][4] = {};
  f32x4 acc2[4][4] = {};

  auto stage_all = [&](int sb, int k0) {          // G = 5 loads/thread
    stS(A, lda, mBase, k0, &sm[sb][0], t);
    stS(B1, K, nBase, k0, &sm[sb][4096], t);
    stS(B1, K, nBase, k0, &sm[sb][4096], t + 512);
    stS(B2, K, nBase, k0, &sm[sb][12288], t);
    stS(B2, K, nBase, k0, &sm[sb][12288], t + 512);
  };

  stage_all(0, 0);
  stage_all(1, 32);

  for (int kt = 0; kt < NT; ++kt) {
    const int cur = kt & 1;
    if (kt + 1 < NT) asm volatile("s_waitcnt vmcnt(5)" ::: "memory");
    else             asm volatile("s_waitcnt vmcnt(0)" ::: "memory");
    __builtin_amdgcn_s_barrier();
    f16x8 af[4], b1v[4], b2v[4];
#pragma unroll
    for (int i = 0; i < 4; ++i)
      af[i] = *(const f16x8*)&sm[cur][idxg(wr * 64 + i * 16 + r16, grp)];
#pragma unroll
    for (int j = 0; j < 4; ++j) {
      int ro = idxg(wcn * 64 + j * 16 + r16, grp);
      b1v[j] = *(const f16x8*)&sm[cur][4096 + ro];
      b2v[j] = *(const f16x8*)&sm[cur][12288 + ro];
    }
    __builtin_amdgcn_s_setprio(1);
#pragma unroll
    for (int i = 0; i < 4; ++i)
#pragma unroll
      for (int j = 0; j < 4; ++j) {
        acc[i][j] = __builtin_amdgcn_mfma_f32_16x16x32_f16(af[i], b1v[j], acc[i][j], 0, 0, 0);
        acc2[i][j] = __builtin_amdgcn_mfma_f32_16x16x32_f16(af[i], b2v[j], acc2[i][j], 0, 0, 0);
      }
    __builtin_amdgcn_s_setprio(0);
    asm volatile("s_waitcnt lgkmcnt(0)" ::: "memory");
    __builtin_amdgcn_s_barrier();
    if (kt + 2 < NT) stage_all(cur, (kt + 2) << 5);
  }

#pragma unroll
  for (int i = 0; i < 4; ++i) {
#pragma unroll
    for (int j = 0; j < 4; ++j) {
#pragma unroll
      for (int r = 0; r < 4; ++r) {
        int row = mBase + wr * 64 + i * 16 + grp * 4 + r;
        int col = nBase + wcn * 64 + j * 16 + r16;
        float a = acc[i][j][r] * RSCL + bias[col];
        float c2 = acc2[i][j][r] * RSCL + bias[2048 + col];
        o16[(size_t)row * ldo + col] = f2h(fgelu(a) * c2 * RSCLI);
      }
    }
  }
}

// ---------------------------------------------------------------------------
extern "C" void kernel_launch(void* const* d_in, const int* in_sizes, int n_in,
                              void* d_out, int out_size, void* d_ws, size_t ws_size,
                              hipStream_t stream) {
  const float* x    = (const float*)d_in[0];
  const float* Wemb = (const float*)d_in[1];
  const float* bemb = (const float*)d_in[2];
  const float* lng  = (const float*)d_in[3];
  const float* lnb  = (const float*)d_in[4];
  const float* Wqkv = (const float*)d_in[5];
  const float* Wout = (const float*)d_in[6];
  const float* bout = (const float*)d_in[7];
  const float* W1   = (const float*)d_in[8];
  const float* b1   = (const float*)d_in[9];
  const float* W2   = (const float*)d_in[10];
  const float* b2   = (const float*)d_in[11];
  const float* Wd   = (const float*)d_in[12];
  const float* bd   = (const float*)d_in[13];

  char* p = (char*)d_ws;
  auto alloc = [&](size_t bytes) {
    char* r = p;
    p += (bytes + 255) & ~(size_t)255;
    return r;
  };
  u16* WembT = (u16*)alloc((size_t)512 * 128 * 2);
  u16* WqkvT = (u16*)alloc((size_t)6 * 1536 * 512 * 2);
  u16* WoutT = (u16*)alloc((size_t)6 * 512 * 512 * 2);
  u16* W1T   = (u16*)alloc((size_t)6 * 4096 * 512 * 2);
  u16* W2T   = (u16*)alloc((size_t)6 * 512 * 2048 * 2);
  u16* WdT   = (u16*)alloc((size_t)128 * 512 * 2);
  float* H   = (float*)alloc((size_t)NTOK * 512 * 4);
  u16* HB    = (u16*)alloc((size_t)NTOK * 512 * 2);
  float* DOTSP = (float*)alloc((size_t)16 * 32 * 4096 * 4);
  float* DOTS  = (float*)alloc((size_t)32 * 4096 * 4);
  char* U = alloc((size_t)64 * 1024 * 1024);
  const size_t MI = 1024 * 1024;
  u16* XP  = (u16*)U;
  u16* Y   = (u16*)U;
  u16* QKV = (u16*)(U + 16 * MI);
  u16* O   = (u16*)U;
  u16* F   = (u16*)U;

  k_transpose<<<dim3(2, 8, 1),  256, 0, stream>>>(Wemb, WembT, 128, 512);
  k_transpose<<<dim3(8, 24, 6), 256, 0, stream>>>(Wqkv, WqkvT, 512, 1536);
  k_transpose<<<dim3(8, 8, 6),  256, 0, stream>>>(Wout, WoutT, 512, 512);
  k_transpose<<<dim3(8, 64, 6), 256, 0, stream>>>(W1, W1T, 512, 4096);
  k_transpose<<<dim3(32, 8, 6), 256, 0, stream>>>(W2, W2T, 2048, 512);
  k_transpose<<<dim3(8, 2, 1),  256, 0, stream>>>(Wd, WdT, 512, 128);

  k_packx<<<8192, 256, 0, stream>>>(x, XP);
  k_gemm<0><<<dim3(4, 128), 256, 0, stream>>>(XP, WembT, 128, bemb,
      nullptr, 1.f, H, nullptr, 0);

  for (int i = 0; i < 6; ++i) {
    k_ln<<<4096, 256, 0, stream>>>(H, lng + i * 512, lnb + i * 512, Y);
    k_gemm<1><<<dim3(12, 128), 256, 0, stream>>>(Y,
        WqkvT + (size_t)i * 1536 * 512, 512, nullptr, nullptr, 1.f,
        nullptr, QKV, 1536);
    k_dots<<<dim3(16, 32), 256, 0, stream>>>(QKV, DOTSP);
    k_reddots<<<512, 256, 0, stream>>>(DOTSP, DOTS);
    k_ov<<<dim3(64, 32), 256, 0, stream>>>(QKV, DOTS, O);
    k_gemm<2><<<dim3(4, 128), 256, 0, stream>>>(O,
        WoutT + (size_t)i * 512 * 512, 512, bout + i * 512, H, 1.f, H, HB, 512);
    k_gemmG<<<dim3(8, 128), 512, 0, stream>>>(HB, 512,
        W1T + (size_t)i * 4096 * 512,
        W1T + (size_t)i * 4096 * 512 + (size_t)2048 * 512, 512,
        b1 + i * 4096, F, 2048);
    k_gemm<2><<<dim3(4, 128), 256, 0, stream>>>(F,
        W2T + (size_t)i * 512 * 2048, 2048, b2 + i * 512, H, RSCL, H, HB, 512);
  }
  k_gemm<7><<<dim3(1, 128), 256, 0, stream>>>(HB, WdT, 512, bd,
      nullptr, 1.f, (float*)d_out, nullptr, 0);
}